// Round 2
// baseline (142.866 us; speedup 1.0000x reference)
//
#include <hip/hip_runtime.h>

#define N_TOK 576          // 24*24 patches per image
#define HP    24
#define PS    16
#define IMG   384
#define ATTN_SCALE 0.35355339059327373f   // 8^-0.5

// ---------------- K1: patchify + first QKV projection (256 -> 8, x3) -------
// one block per (b, patch); thread t = feature index (iy*16+ix)
__global__ __launch_bounds__(256) void k_qkv1(
    const float* __restrict__ x,
    const float* __restrict__ Wq, const float* __restrict__ bq,
    const float* __restrict__ Wk, const float* __restrict__ bk,
    const float* __restrict__ Wv, const float* __restrict__ bv,
    float* __restrict__ q1, float* __restrict__ k1, float* __restrict__ v1)
{
    const int blk = blockIdx.x;           // b*576 + n
    const int b  = blk / N_TOK;
    const int n  = blk % N_TOK;
    const int py = n / HP, px = n % HP;
    const int t  = threadIdx.x;           // 0..255
    const int iy = t >> 4, ix = t & 15;

    const float pv = x[b*IMG*IMG + (py*PS + iy)*IMG + (px*PS + ix)];

    float acc[24];
#pragma unroll
    for (int h = 0; h < 8; ++h) {
        acc[h]      = pv * Wq[t*8 + h];
        acc[8 + h]  = pv * Wk[t*8 + h];
        acc[16 + h] = pv * Wv[t*8 + h];
    }
#pragma unroll
    for (int off = 32; off > 0; off >>= 1) {
#pragma unroll
        for (int j = 0; j < 24; ++j)
            acc[j] += __shfl_down(acc[j], off);
    }
    __shared__ float red[4][24];
    const int lane = t & 63, w = t >> 6;
    if (lane == 0) {
#pragma unroll
        for (int j = 0; j < 24; ++j) red[w][j] = acc[j];
    }
    __syncthreads();
    if (t < 24) {
        float s = red[0][t] + red[1][t] + red[2][t] + red[3][t];
        const int h = t & 7, mat = t >> 3;
        const float* bias = (mat == 0) ? bq : (mat == 1) ? bk : bv;
        float* dst = (mat == 0) ? q1 : (mat == 1) ? k1 : v1;
        dst[(b*N_TOK + n)*8 + h] = s + bias[h];
    }
}

// ---------------- K2: attention 1 + fused QKV2 projection ------------------
// one wave per token; 576 keys = 9 chunks of 64
__global__ __launch_bounds__(256) void k_attn1(
    const float* __restrict__ q1, const float* __restrict__ k1, const float* __restrict__ v1,
    const float* __restrict__ Wsq, const float* __restrict__ bsq,
    const float* __restrict__ Wsk, const float* __restrict__ bsk,
    const float* __restrict__ Wsv, const float* __restrict__ bsv,
    float* __restrict__ q2, float* __restrict__ k2, float* __restrict__ v2)
{
    const int lane = threadIdx.x & 63;
    const int wv   = threadIdx.x >> 6;
    const int tok  = blockIdx.x*4 + wv;     // 0..1151
    const int b    = tok / N_TOK;

    float qv[8];
#pragma unroll
    for (int h = 0; h < 8; ++h) qv[h] = q1[tok*8 + h];

    const float* kb = k1 + b*N_TOK*8;
    const float* vb = v1 + b*N_TOK*8;

    float sc[9], mx = -1e30f;
#pragma unroll
    for (int ch = 0; ch < 9; ++ch) {
        const float* kp = kb + (ch*64 + lane)*8;
        float d = 0.f;
#pragma unroll
        for (int h = 0; h < 8; ++h) d += qv[h]*kp[h];
        d *= ATTN_SCALE;
        sc[ch] = d;
        mx = fmaxf(mx, d);
    }
#pragma unroll
    for (int off = 32; off > 0; off >>= 1) mx = fmaxf(mx, __shfl_xor(mx, off));

    float ssum = 0.f, o[8];
#pragma unroll
    for (int h = 0; h < 8; ++h) o[h] = 0.f;
#pragma unroll
    for (int ch = 0; ch < 9; ++ch) {
        const float p = __expf(sc[ch] - mx);
        ssum += p;
        const float* vp = vb + (ch*64 + lane)*8;
#pragma unroll
        for (int h = 0; h < 8; ++h) o[h] += p*vp[h];
    }
#pragma unroll
    for (int off = 32; off > 0; off >>= 1) {
        ssum += __shfl_xor(ssum, off);
#pragma unroll
        for (int h = 0; h < 8; ++h) o[h] += __shfl_xor(o[h], off);
    }
    const float inv = 1.f/ssum;
    float f[8];
#pragma unroll
    for (int h = 0; h < 8; ++h) f[h] = o[h]*inv;

    if (lane < 24) {
        const int mat = lane >> 3, h = lane & 7;
        const float* Wm = (mat==0)?Wsq:(mat==1)?Wsk:Wsv;
        const float* bm = (mat==0)?bsq:(mat==1)?bsk:bsv;
        float s = bm[h];
#pragma unroll
        for (int j = 0; j < 8; ++j) s += f[j]*Wm[j*8 + h];
        float* dst = (mat==0)?q2:(mat==1)?k2:v2;
        dst[tok*8 + h] = s;
    }
}

// ---------------- K3: attention 2 + LayerNorm + BoundedSoftplus sigmas -----
__global__ __launch_bounds__(256) void k_attn2(
    const float* __restrict__ q2, const float* __restrict__ k2, const float* __restrict__ v2,
    const float* __restrict__ ln_g, const float* __restrict__ ln_b,
    const float* __restrict__ Wp,   const float* __restrict__ bp,
    float* __restrict__ sig, int* __restrict__ smax)
{
    const int lane = threadIdx.x & 63;
    const int wv   = threadIdx.x >> 6;
    const int tok  = blockIdx.x*4 + wv;
    const int b    = tok / N_TOK;

    float qv[8];
#pragma unroll
    for (int h = 0; h < 8; ++h) qv[h] = q2[tok*8 + h];

    const float* kb = k2 + b*N_TOK*8;
    const float* vb = v2 + b*N_TOK*8;

    float sc[9], mx = -1e30f;
#pragma unroll
    for (int ch = 0; ch < 9; ++ch) {
        const float* kp = kb + (ch*64 + lane)*8;
        float d = 0.f;
#pragma unroll
        for (int h = 0; h < 8; ++h) d += qv[h]*kp[h];
        d *= ATTN_SCALE;
        sc[ch] = d;
        mx = fmaxf(mx, d);
    }
#pragma unroll
    for (int off = 32; off > 0; off >>= 1) mx = fmaxf(mx, __shfl_xor(mx, off));

    float ssum = 0.f, o[8];
#pragma unroll
    for (int h = 0; h < 8; ++h) o[h] = 0.f;
#pragma unroll
    for (int ch = 0; ch < 9; ++ch) {
        const float p = __expf(sc[ch] - mx);
        ssum += p;
        const float* vp = vb + (ch*64 + lane)*8;
#pragma unroll
        for (int h = 0; h < 8; ++h) o[h] += p*vp[h];
    }
#pragma unroll
    for (int off = 32; off > 0; off >>= 1) {
        ssum += __shfl_xor(ssum, off);
#pragma unroll
        for (int h = 0; h < 8; ++h) o[h] += __shfl_xor(o[h], off);
    }

    if (lane == 0) {
        const float inv = 1.f/ssum;
        float f[8];
        float mu = 0.f;
#pragma unroll
        for (int h = 0; h < 8; ++h) { f[h] = o[h]*inv; mu += f[h]; }
        mu *= 0.125f;
        float var = 0.f;
#pragma unroll
        for (int h = 0; h < 8; ++h) { const float d = f[h]-mu; var += d*d; }
        var *= 0.125f;
        const float rinv = rsqrtf(var + 1e-5f);
        float on[8];
#pragma unroll
        for (int h = 0; h < 8; ++h)
            on[h] = (f[h]-mu)*rinv*ln_g[h] + ln_b[h];
        float sv[3];
#pragma unroll
        for (int c = 0; c < 3; ++c) {
            float z = bp[c];
#pragma unroll
            for (int j = 0; j < 8; ++j) z += on[j]*Wp[j*3 + c];
            const float sp = (z > 20.f) ? z : log1pf(__expf(z));
            sv[c] = fminf(sp, 6.0f) + 1e-6f;
            sig[tok*3 + c] = sv[c];
        }
        atomicMax(smax, __float_as_int(fmaxf(sv[0], sv[1])));
    }
}

// ---------------- K4: derive half = ceil(m+1); k = 2*half+1 (always odd) ---
__global__ void k_half(const int* __restrict__ smaxi, int* __restrict__ halfp)
{
    const float m = __int_as_float(*smaxi);
    int h = (int)ceilf(m + 1.0f);
    if (h < 1) h = 1;
    if (h > 8) h = 8;        // sigma cap 6 -> h <= 8 always; guard LDS tile
    halfp[0] = h;
}

// ---------------- K5: bilateral filter, one block per 16x16 patch ----------
// sigmas are uniform within a patch -> block-uniform coefficients.
// LDS tile stride 40: row shift = 8 banks -> only the inherent 2-way
// (64 lanes / 32 banks) aliasing, which is free.
__global__ __launch_bounds__(256) void k_bilat(
    const float* __restrict__ x, const float* __restrict__ sig,
    const int* __restrict__ halfp, float* __restrict__ out)
{
    __shared__ float tile[32*40];
    const int blk = blockIdx.x;           // b*576 + n
    const int b  = blk / N_TOK;
    const int n  = blk % N_TOK;
    const int py = n / HP, px = n % HP;
    const int tx = threadIdx.x & 15, ty = threadIdx.x >> 4;

    const int half = halfp[0];            // <= 8 (sigma capped at 6)
    const float sx = sig[blk*3 + 0];
    const float sy = sig[blk*3 + 1];
    const float sr = sig[blk*3 + 2];

    const int tilew = PS + 2*half;
    const float* xb = x + b*IMG*IMG;
    for (int yy = ty; yy < tilew; yy += 16) {
        const int gy = py*PS + yy - half;
        for (int xx = tx; xx < tilew; xx += 16) {
            const int gx = px*PS + xx - half;
            float v = 0.f;                 // zero padding, included in sums
            if ((unsigned)gy < IMG && (unsigned)gx < IMG)
                v = xb[gy*IMG + gx];
            tile[yy*40 + xx] = v;
        }
    }
    __syncthreads();

    const float c  = tile[(ty+half)*40 + (tx+half)];
    const float ax = -0.5f/(sx*sx);
    const float ay = -0.5f/(sy*sy);
    const float ar = -0.5f/(sr*sr);

    float num = 0.f, den = 0.f;
    const int k = 2*half + 1;
    for (int dy = 0; dy < k; ++dy) {
        const float fy = (float)(dy - half);
        const float ey = ay*fy*fy;
        const float* row = &tile[(ty+dy)*40 + tx];
        for (int dx = 0; dx < k; ++dx) {
            const float fx = (float)(dx - half);
            const float p  = row[dx];
            const float d  = c - p;
            const float w  = __expf(ey + ax*fx*fx + ar*d*d);  // sp*rg fused
            den += w;
            num += w*p;
        }
    }
    out[b*IMG*IMG + (py*PS + ty)*IMG + (px*PS + tx)] = num/(den + 1e-8f);
}

// ---------------- launch ---------------------------------------------------
extern "C" void kernel_launch(void* const* d_in, const int* in_sizes, int n_in,
                              void* d_out, int out_size, void* d_ws, size_t ws_size,
                              hipStream_t stream)
{
    const float* x    = (const float*)d_in[0];
    const float* Wq   = (const float*)d_in[1];
    const float* bq   = (const float*)d_in[2];
    const float* Wk   = (const float*)d_in[3];
    const float* bk   = (const float*)d_in[4];
    const float* Wv   = (const float*)d_in[5];
    const float* bv   = (const float*)d_in[6];
    const float* Wsq  = (const float*)d_in[7];
    const float* bsq  = (const float*)d_in[8];
    const float* Wsk  = (const float*)d_in[9];
    const float* bsk  = (const float*)d_in[10];
    const float* Wsv  = (const float*)d_in[11];
    const float* bsv  = (const float*)d_in[12];
    const float* ln_g = (const float*)d_in[13];
    const float* ln_b = (const float*)d_in[14];
    const float* Wp   = (const float*)d_in[15];
    const float* bp   = (const float*)d_in[16];

    float* W  = (float*)d_ws;
    float* q1 = W;            // 2*576*8 = 9216 each
    float* k1 = W +  9216;
    float* v1 = W + 18432;
    float* q2 = W + 27648;
    float* k2 = W + 36864;
    float* v2 = W + 46080;
    float* sg = W + 55296;    // 2*576*3 = 3456
    int* smax = (int*)(W + 58752);
    int* halfp = smax + 1;

    hipMemsetAsync(smax, 0, 2*sizeof(int), stream);

    k_qkv1<<<2*N_TOK, 256, 0, stream>>>(x, Wq, bq, Wk, bk, Wv, bv, q1, k1, v1);
    k_attn1<<<2*N_TOK/4, 256, 0, stream>>>(q1, k1, v1, Wsq, bsq, Wsk, bsk, Wsv, bsv,
                                           q2, k2, v2);
    k_attn2<<<2*N_TOK/4, 256, 0, stream>>>(q2, k2, v2, ln_g, ln_b, Wp, bp, sg, smax);
    k_half<<<1, 1, 0, stream>>>(smax, halfp);
    k_bilat<<<2*N_TOK, 256, 0, stream>>>(x, sg, halfp, (float*)d_out);
}